// Round 1
// baseline (192.377 us; speedup 1.0000x reference)
//
#include <hip/hip_runtime.h>

typedef _Float16 half_t;
typedef _Float16 half8 __attribute__((ext_vector_type(8)));
typedef _Float16 half4 __attribute__((ext_vector_type(4)));
typedef float floatx4 __attribute__((ext_vector_type(4)));
typedef float floatx16 __attribute__((ext_vector_type(16)));

#define C1 0.72134752044448170368f   /* 2*log2(e)/SCALE, SCALE=4 */
#define C2 14.4269504088896340736f   /* 10*log2(e) */
#define C3 28.8539008177792681472f   /* 20*log2(e) */

__device__ __forceinline__ floatx4 zero4() {
    floatx4 z; z[0] = z[1] = z[2] = z[3] = 0.f; return z;
}
__device__ __forceinline__ floatx16 zero16() {
    floatx16 z;
#pragma unroll
    for (int i = 0; i < 16; ++i) z[i] = 0.f;
    return z;
}

// p = exp(10*tanh(s)) computed as exp2(b - C3 * rcp(exp2(S') + 1)),
// S' = 2*log2e*s (folded into Wq), b = C2 (unmasked) or -1e30 (masked -> p=0).
__device__ __forceinline__ float pfun(float sp, float b) {
    float u = __builtin_amdgcn_exp2f(sp);
    float r = __builtin_amdgcn_rcpf(u + 1.0f);
    return __builtin_amdgcn_exp2f(b - C3 * r);
}

// ---------------- k0: convert weights to fp16 (Wq pre-scaled by C1) --------
__global__ void k_convw(const float* __restrict__ Wq, const float* __restrict__ Wk,
                        const float* __restrict__ Wv, const float* __restrict__ Wo,
                        half_t* __restrict__ Wh) {
    int idx = blockIdx.x * 256 + threadIdx.x;      // 0..65535
    int which = idx >> 14;
    int off = idx & 16383;
    const float* src = (which == 0) ? Wq : (which == 1) ? Wk : (which == 2) ? Wv : Wo;
    float scale = (which == 0) ? C1 : 1.0f;
    Wh[idx] = (half_t)(src[off] * scale);
}

// ---------------- k1: QKV projections, output layout (bc, h, n, 16) --------
__global__ __launch_bounds__(256) void k_proj(
        const float* __restrict__ Q, const float* __restrict__ K,
        const float* __restrict__ V, const half_t* __restrict__ WhBase,
        half_t* __restrict__ qw, half_t* __restrict__ kw, half_t* __restrict__ vw) {
    int which = blockIdx.y;
    const float* X = (which == 0) ? Q : (which == 1) ? K : V;
    const half_t* W = WhBase + which * 16384;
    half_t* Y = (which == 0) ? qw : (which == 1) ? kw : vw;

    int tid = threadIdx.x;
    int w = tid >> 6, lane = tid & 63;
    int l15 = lane & 15, quad = lane >> 4;
    int rowbase = blockIdx.x * 64 + w * 16;
    int arow = rowbase + l15;

    floatx4 acc[8];
#pragma unroll
    for (int nt = 0; nt < 8; ++nt) acc[nt] = zero4();

#pragma unroll
    for (int ks = 0; ks < 4; ++ks) {
        const float* ap = X + arow * 128 + ks * 32 + quad * 8;
        float4 a0 = *(const float4*)ap;
        float4 a1 = *(const float4*)(ap + 4);
        half8 af;
        af[0] = (half_t)a0.x; af[1] = (half_t)a0.y; af[2] = (half_t)a0.z; af[3] = (half_t)a0.w;
        af[4] = (half_t)a1.x; af[5] = (half_t)a1.y; af[6] = (half_t)a1.z; af[7] = (half_t)a1.w;
#pragma unroll
        for (int nt = 0; nt < 8; ++nt) {
            half8 bf = *(const half8*)(W + (nt * 16 + l15) * 128 + ks * 32 + quad * 8);
            acc[nt] = __builtin_amdgcn_mfma_f32_16x16x32_f16(af, bf, acc[nt], 0, 0, 0);
        }
    }
    // C/D: row = quad*4 + r, col = l15. n-tile == head (both 16 wide).
#pragma unroll
    for (int nt = 0; nt < 8; ++nt) {
#pragma unroll
        for (int r = 0; r < 4; ++r) {
            int R = rowbase + quad * 4 + r;      // global row = bc*512 + n
            int bc = R >> 9, n = R & 511;
            Y[((bc * 8 + nt) * 512 + n) * 16 + l15] = (half_t)acc[nt][r];
        }
    }
}

// ---------------- k2: fused attention, one block per (bc, h) ---------------
__global__ __launch_bounds__(256, 2) void k_attn(
        const half_t* __restrict__ qg, const half_t* __restrict__ kg,
        const half_t* __restrict__ vg, const int* __restrict__ mask,
        half_t* __restrict__ attn) {
    __shared__ float bias[512];
    __shared__ half_t vT[16 * 520];          // v transposed, padded stride
    __shared__ half_t Pl[4][128 * 44];       // per-wave P, row stride 44 halves

    int bch = blockIdx.x;
    int bc = bch >> 3, h = bch & 7;
    int tid = threadIdx.x;
    int w = tid >> 6, lane = tid & 63;
    int l31 = lane & 31, hf = lane >> 5;
    int l15 = lane & 15, quad = lane >> 4;

    const half_t* qh = qg + bch * 8192;
    const half_t* kh = kg + bch * 8192;
    const half_t* vh = vg + bch * 8192;

    for (int i = tid; i < 512; i += 256)
        bias[i] = mask[bc * 512 + i] ? -1.0e30f : C2;
    for (int r = tid; r < 512; r += 256) {
        half8 v0 = *(const half8*)(vh + r * 16);
        half8 v1 = *(const half8*)(vh + r * 16 + 8);
#pragma unroll
        for (int d = 0; d < 8; ++d) vT[d * 520 + r] = v0[d];
#pragma unroll
        for (int d = 0; d < 8; ++d) vT[(d + 8) * 520 + r] = v1[d];
    }
    __syncthreads();

    // Q B-fragments: lane holds q[qrow = l31][d = hf*8 + j]
    half8 qf[4];
#pragma unroll
    for (int t = 0; t < 4; ++t)
        qf[t] = *(const half8*)(qh + ((w * 4 + t) * 32 + l31) * 16 + hf * 8);

    floatx4 O[8];
#pragma unroll
    for (int nt = 0; nt < 8; ++nt) O[nt] = zero4();
    float rs[4] = {0.f, 0.f, 0.f, 0.f};
    half_t* Pw = &Pl[w][0];

#pragma unroll 1
    for (int c = 0; c < 16; ++c) {
        // K A-fragment: A[key = c*32 + l31][d = hf*8 + j]
        half8 kf = *(const half8*)(kh + (c * 32 + l31) * 16 + hf * 8);
        // V^T A-fragment for PV: A[d = l15][key = c*32 + quad*8 + j]
        half8 vf = *(const half8*)(&vT[l15 * 520 + c * 32 + quad * 8]);
        const float4* b4 = (const float4*)bias;
        float4 bv[4];
#pragma unroll
        for (int g = 0; g < 4; ++g) bv[g] = b4[c * 8 + hf + 2 * g];

#pragma unroll
        for (int t = 0; t < 4; ++t) {
            // S^T tile: D[key][qrow], key = (r&3)+8*(r>>2)+4*hf, qrow = t*32+l31
            floatx16 S = __builtin_amdgcn_mfma_f32_32x32x16_f16(kf, qf[t], zero16(), 0, 0, 0);
            int prow = (t * 32 + l31) * 44;
            float rsum = 0.f;
#pragma unroll
            for (int g = 0; g < 4; ++g) {
                float p0 = pfun(S[4 * g + 0], bv[g].x);
                float p1 = pfun(S[4 * g + 1], bv[g].y);
                float p2 = pfun(S[4 * g + 2], bv[g].z);
                float p3 = pfun(S[4 * g + 3], bv[g].w);
                rsum += (p0 + p1) + (p2 + p3);
                half4 ph;
                ph[0] = (half_t)p0; ph[1] = (half_t)p1;
                ph[2] = (half_t)p2; ph[3] = (half_t)p3;
                // P[qrow][key], keys 8g+4hf+0..3 -> packed 8B store
                *(half4*)(Pw + prow + hf * 4 + g * 8) = ph;
            }
            rs[t] += rsum;
        }
        // O^T += V^T * P^T (per-wave LDS, no barrier needed)
#pragma unroll
        for (int nt = 0; nt < 8; ++nt) {
            half8 pb = *(const half8*)(Pw + (nt * 16 + l15) * 44 + quad * 8);
            O[nt] = __builtin_amdgcn_mfma_f32_16x16x32_f16(vf, pb, O[nt], 0, 0, 0);
        }
    }

    // row sums: lane partial covers its half's 256 keys for qrow = t*32 + l31
    float inv[4];
#pragma unroll
    for (int t = 0; t < 4; ++t) {
        float r2 = rs[t] + __shfl_xor(rs[t], 32, 64);
        inv[t] = __builtin_amdgcn_rcpf(r2);
    }
    // O^T C/D: row = d = quad*4 + r, col = qrow = nt*16 + l15
#pragma unroll
    for (int nt = 0; nt < 8; ++nt) {
        float iv = __shfl(inv[nt >> 1], ((nt & 1) << 4) | l15, 64);
        int qrow = w * 128 + nt * 16 + l15;
        half4 ov;
        ov[0] = (half_t)(O[nt][0] * iv);
        ov[1] = (half_t)(O[nt][1] * iv);
        ov[2] = (half_t)(O[nt][2] * iv);
        ov[3] = (half_t)(O[nt][3] * iv);
        *(half4*)(attn + (bc * 512 + qrow) * 128 + h * 16 + quad * 4) = ov;
    }
}

// ---------------- k3: output projection -> fp32 ----------------------------
__global__ __launch_bounds__(256) void k_out(
        const half_t* __restrict__ A, const half_t* __restrict__ Wh,
        float* __restrict__ out) {
    int tid = threadIdx.x;
    int w = tid >> 6, lane = tid & 63;
    int l15 = lane & 15, quad = lane >> 4;
    int rowbase = blockIdx.x * 64 + w * 16;

    floatx4 acc[8];
#pragma unroll
    for (int nt = 0; nt < 8; ++nt) acc[nt] = zero4();
#pragma unroll
    for (int ks = 0; ks < 4; ++ks) {
        half8 af = *(const half8*)(A + (rowbase + l15) * 128 + ks * 32 + quad * 8);
#pragma unroll
        for (int nt = 0; nt < 8; ++nt) {
            half8 bf = *(const half8*)(Wh + (nt * 16 + l15) * 128 + ks * 32 + quad * 8);
            acc[nt] = __builtin_amdgcn_mfma_f32_16x16x32_f16(af, bf, acc[nt], 0, 0, 0);
        }
    }
#pragma unroll
    for (int nt = 0; nt < 8; ++nt)
#pragma unroll
        for (int r = 0; r < 4; ++r)
            out[(rowbase + quad * 4 + r) * 128 + nt * 16 + l15] = acc[nt][r];
}

extern "C" void kernel_launch(void* const* d_in, const int* in_sizes, int n_in,
                              void* d_out, int out_size, void* d_ws, size_t ws_size,
                              hipStream_t stream) {
    const float* Q    = (const float*)d_in[0];
    const float* K    = (const float*)d_in[1];
    const float* V    = (const float*)d_in[2];
    const int*   mask = (const int*)d_in[3];
    const float* Wq   = (const float*)d_in[4];
    const float* Wk   = (const float*)d_in[5];
    const float* Wv   = (const float*)d_in[6];
    const float* Wo   = (const float*)d_in[7];
    float* out = (float*)d_out;

    half_t* ws = (half_t*)d_ws;
    half_t* Wh = ws;                       // 65536 halves (4 x 128x128)
    half_t* qw = ws + 65536;               // 32768*128
    half_t* kw = qw + 4194304;
    half_t* vw = kw + 4194304;
    half_t* aw = vw + 4194304;

    k_convw<<<256, 256, 0, stream>>>(Wq, Wk, Wv, Wo, Wh);
    k_proj<<<dim3(512, 3), 256, 0, stream>>>(Q, K, V, Wh, qw, kw, vw);
    k_attn<<<512, 256, 0, stream>>>(qw, kw, vw, mask, aw);
    k_out<<<512, 256, 0, stream>>>(aw, Wh + 49152, out);
}

// Round 2
// 188.169 us; speedup vs baseline: 1.0224x; 1.0224x over previous
//
#include <hip/hip_runtime.h>

typedef _Float16 half_t;
typedef _Float16 half8 __attribute__((ext_vector_type(8)));
typedef _Float16 half4 __attribute__((ext_vector_type(4)));
typedef float floatx4 __attribute__((ext_vector_type(4)));
typedef float floatx16 __attribute__((ext_vector_type(16)));

#define C1 0.72134752044448170368f   /* 2*log2(e)/SCALE, SCALE=4 */
#define C2 14.4269504088896340736f   /* 10*log2(e) */
#define C3 28.8539008177792681472f   /* 20*log2(e) */

__device__ __forceinline__ floatx4 zero4() {
    floatx4 z; z[0] = z[1] = z[2] = z[3] = 0.f; return z;
}
__device__ __forceinline__ floatx16 zero16() {
    floatx16 z;
#pragma unroll
    for (int i = 0; i < 16; ++i) z[i] = 0.f;
    return z;
}

// p = exp(10*tanh(s)) computed as exp2(b - C3 * rcp(exp2(S') + 1)),
// S' = 2*log2e*s (folded into Wq), b = C2 (unmasked) or -1e30 (masked -> p=0).
__device__ __forceinline__ float pfun(float sp, float b) {
    float u = __builtin_amdgcn_exp2f(sp);
    float r = __builtin_amdgcn_rcpf(u + 1.0f);
    return __builtin_amdgcn_exp2f(b - C3 * r);
}

// ---------------- k0: convert weights to fp16 (Wq pre-scaled by C1) --------
__global__ void k_convw(const float* __restrict__ Wq, const float* __restrict__ Wk,
                        const float* __restrict__ Wv, const float* __restrict__ Wo,
                        half_t* __restrict__ Wh) {
    int idx = blockIdx.x * 256 + threadIdx.x;      // 0..65535
    int which = idx >> 14;
    int off = idx & 16383;
    const float* src = (which == 0) ? Wq : (which == 1) ? Wk : (which == 2) ? Wv : Wo;
    float scale = (which == 0) ? C1 : 1.0f;
    Wh[idx] = (half_t)(src[off] * scale);
}

// ---------------- k1: QKV projections -------------------------------------
// Q,K: operand-swapped (A=W, B=X) -> D[f][token], half4 stores into
//      layout (bc, h, n, 16).
// V:   original order (A=X, B=W) -> D[token][f], half4 stores into
//      TRANSPOSED layout (bc, h, d, n) consumed directly by k_attn's PV MFMA.
__global__ __launch_bounds__(256) void k_proj(
        const float* __restrict__ Q, const float* __restrict__ K,
        const float* __restrict__ V, const half_t* __restrict__ WhBase,
        half_t* __restrict__ qw, half_t* __restrict__ kw, half_t* __restrict__ vw) {
    int which = blockIdx.y;
    const float* X = (which == 0) ? Q : (which == 1) ? K : V;
    const half_t* W = WhBase + which * 16384;

    int tid = threadIdx.x;
    int w = tid >> 6, lane = tid & 63;
    int l15 = lane & 15, quad = lane >> 4;
    int tokbase = blockIdx.x * 64 + w * 16;

    floatx4 acc[8];
#pragma unroll
    for (int nt = 0; nt < 8; ++nt) acc[nt] = zero4();

#pragma unroll
    for (int ks = 0; ks < 4; ++ks) {
        const float* ap = X + (tokbase + l15) * 128 + ks * 32 + quad * 8;
        float4 a0 = *(const float4*)ap;
        float4 a1 = *(const float4*)(ap + 4);
        half8 xf;
        xf[0] = (half_t)a0.x; xf[1] = (half_t)a0.y; xf[2] = (half_t)a0.z; xf[3] = (half_t)a0.w;
        xf[4] = (half_t)a1.x; xf[5] = (half_t)a1.y; xf[6] = (half_t)a1.z; xf[7] = (half_t)a1.w;
        if (which == 2) {
#pragma unroll
            for (int nt = 0; nt < 8; ++nt) {
                half8 wf = *(const half8*)(W + (nt * 16 + l15) * 128 + ks * 32 + quad * 8);
                acc[nt] = __builtin_amdgcn_mfma_f32_16x16x32_f16(xf, wf, acc[nt], 0, 0, 0);
            }
        } else {
#pragma unroll
            for (int nt = 0; nt < 8; ++nt) {
                half8 wf = *(const half8*)(W + (nt * 16 + l15) * 128 + ks * 32 + quad * 8);
                acc[nt] = __builtin_amdgcn_mfma_f32_16x16x32_f16(wf, xf, acc[nt], 0, 0, 0);
            }
        }
    }

    if (which == 2) {
        // D[token = quad*4+r][f = l15]; transposed store (bc, h, d, n)
        int R0 = tokbase + quad * 4;
        int bc = R0 >> 9, n0 = R0 & 511;
#pragma unroll
        for (int nt = 0; nt < 8; ++nt) {
            half4 hv;
            hv[0] = (half_t)acc[nt][0]; hv[1] = (half_t)acc[nt][1];
            hv[2] = (half_t)acc[nt][2]; hv[3] = (half_t)acc[nt][3];
            *(half4*)(vw + ((bc * 8 + nt) * 16 + l15) * 512 + n0) = hv;
        }
    } else {
        // D[f = quad*4+r][token = l15]; store (bc, h, n, 16)
        int R = tokbase + l15;
        int bc = R >> 9, n = R & 511;
        half_t* Y = (which == 0) ? qw : kw;
#pragma unroll
        for (int nt = 0; nt < 8; ++nt) {
            half4 hv;
            hv[0] = (half_t)acc[nt][0]; hv[1] = (half_t)acc[nt][1];
            hv[2] = (half_t)acc[nt][2]; hv[3] = (half_t)acc[nt][3];
            *(half4*)(Y + ((bc * 8 + nt) * 512 + n) * 16 + quad * 4) = hv;
        }
    }
}

// ---------------- k2: fused attention, one block per (bc, h, q-half) ------
__global__ __launch_bounds__(256, 4) void k_attn(
        const half_t* __restrict__ qg, const half_t* __restrict__ kg,
        const half_t* __restrict__ vTg, const int* __restrict__ mask,
        half_t* __restrict__ attn) {
    __shared__ float bias[512];
    __shared__ half_t Pl[4][32 * 36];        // per-wave P tile, row stride 36

    int bx = blockIdx.x;
    int bch = bx >> 1, qhi = bx & 1;
    int bc = bch >> 3, h = bch & 7;
    int tid = threadIdx.x;
    int w = tid >> 6, lane = tid & 63;
    int l31 = lane & 31, hf = lane >> 5;
    int l15 = lane & 15, quad = lane >> 4;

    const half_t* qh = qg + bch * 8192;
    const half_t* kh = kg + bch * 8192;
    const half_t* vh = vTg + bch * 8192;     // (d, n): d*512 + n

    for (int i = tid; i < 512; i += 256)
        bias[i] = mask[bc * 512 + i] ? -1.0e30f : C2;
    __syncthreads();

    int qbase = qhi * 256 + w * 64;
    // Q B-fragments (32x32x16): lane holds q[qrow = l31][d = hf*8 + j]
    half8 qf[2];
#pragma unroll
    for (int t = 0; t < 2; ++t)
        qf[t] = *(const half8*)(qh + (qbase + t * 32 + l31) * 16 + hf * 8);

    floatx4 O[4];
#pragma unroll
    for (int nt = 0; nt < 4; ++nt) O[nt] = zero4();
    float rs[2] = {0.f, 0.f};
    half_t* Pw = &Pl[w][0];
    const float4* b4 = (const float4*)bias;

#pragma unroll 1
    for (int c = 0; c < 16; ++c) {
        // K A-fragment: A[key = c*32 + l31][d = hf*8 + j]
        half8 kf = *(const half8*)(kh + (c * 32 + l31) * 16 + hf * 8);
        // V^T A-fragment for PV: A[d = l15][key = c*32 + quad*8 + j]
        half8 vf = *(const half8*)(vh + l15 * 512 + c * 32 + quad * 8);
        float4 bv[4];
#pragma unroll
        for (int g = 0; g < 4; ++g) bv[g] = b4[c * 8 + hf + 2 * g];

#pragma unroll
        for (int t = 0; t < 2; ++t) {
            // S^T tile: D[key][qrow], key = 8*(r>>2) + 4*hf + (r&3), qrow-local = l31
            floatx16 S = __builtin_amdgcn_mfma_f32_32x32x16_f16(kf, qf[t], zero16(), 0, 0, 0);
            float rsum = 0.f;
#pragma unroll
            for (int g = 0; g < 4; ++g) {
                float p0 = pfun(S[4 * g + 0], bv[g].x);
                float p1 = pfun(S[4 * g + 1], bv[g].y);
                float p2 = pfun(S[4 * g + 2], bv[g].z);
                float p3 = pfun(S[4 * g + 3], bv[g].w);
                rsum += (p0 + p1) + (p2 + p3);
                half4 ph;
                ph[0] = (half_t)p0; ph[1] = (half_t)p1;
                ph[2] = (half_t)p2; ph[3] = (half_t)p3;
                *(half4*)(Pw + l31 * 36 + hf * 4 + g * 8) = ph;
            }
            rs[t] += rsum;
            // O^T += V^T * P^T for the two 16-col tiles of this 32-row P tile
#pragma unroll
            for (int nt2 = 0; nt2 < 2; ++nt2) {
                half8 pb = *(const half8*)(Pw + (nt2 * 16 + l15) * 36 + quad * 8);
                O[2 * t + nt2] = __builtin_amdgcn_mfma_f32_16x16x32_f16(vf, pb, O[2 * t + nt2], 0, 0, 0);
            }
        }
    }

    float inv[2];
#pragma unroll
    for (int t = 0; t < 2; ++t) {
        float r2 = rs[t] + __shfl_xor(rs[t], 32, 64);
        inv[t] = __builtin_amdgcn_rcpf(r2);
    }
    // O^T C/D: row = d = quad*4 + r, col = qrow-local = nt*16 + l15
#pragma unroll
    for (int nt = 0; nt < 4; ++nt) {
        float iv = __shfl(inv[nt >> 1], ((nt & 1) << 4) | l15, 64);
        int qrow = qbase + nt * 16 + l15;
        half4 ov;
        ov[0] = (half_t)(O[nt][0] * iv);
        ov[1] = (half_t)(O[nt][1] * iv);
        ov[2] = (half_t)(O[nt][2] * iv);
        ov[3] = (half_t)(O[nt][3] * iv);
        *(half4*)(attn + (bc * 512 + qrow) * 128 + h * 16 + quad * 4) = ov;
    }
}

// ---------------- k3: output projection -> fp32 (operand-swapped) ----------
__global__ __launch_bounds__(256) void k_out(
        const half_t* __restrict__ A, const half_t* __restrict__ Wh,
        float* __restrict__ out) {
    int tid = threadIdx.x;
    int w = tid >> 6, lane = tid & 63;
    int l15 = lane & 15, quad = lane >> 4;
    int tokbase = blockIdx.x * 64 + w * 16;

    floatx4 acc[8];
#pragma unroll
    for (int nt = 0; nt < 8; ++nt) acc[nt] = zero4();
#pragma unroll
    for (int ks = 0; ks < 4; ++ks) {
        half8 xf = *(const half8*)(A + (tokbase + l15) * 128 + ks * 32 + quad * 8);
#pragma unroll
        for (int nt = 0; nt < 8; ++nt) {
            half8 wf = *(const half8*)(Wh + (nt * 16 + l15) * 128 + ks * 32 + quad * 8);
            acc[nt] = __builtin_amdgcn_mfma_f32_16x16x32_f16(wf, xf, acc[nt], 0, 0, 0);
        }
    }
    // D[f = nt*16 + quad*4 + r][token = l15] -> float4 stores
#pragma unroll
    for (int nt = 0; nt < 8; ++nt) {
        float4 o;
        o.x = acc[nt][0]; o.y = acc[nt][1]; o.z = acc[nt][2]; o.w = acc[nt][3];
        *(float4*)(out + (tokbase + l15) * 128 + nt * 16 + quad * 4) = o;
    }
}

extern "C" void kernel_launch(void* const* d_in, const int* in_sizes, int n_in,
                              void* d_out, int out_size, void* d_ws, size_t ws_size,
                              hipStream_t stream) {
    const float* Q    = (const float*)d_in[0];
    const float* K    = (const float*)d_in[1];
    const float* V    = (const float*)d_in[2];
    const int*   mask = (const int*)d_in[3];
    const float* Wq   = (const float*)d_in[4];
    const float* Wk   = (const float*)d_in[5];
    const float* Wv   = (const float*)d_in[6];
    const float* Wo   = (const float*)d_in[7];
    float* out = (float*)d_out;

    half_t* ws = (half_t*)d_ws;
    half_t* Wh = ws;                       // 65536 halves (4 x 128x128)
    half_t* qw = ws + 65536;               // each 4194304 halves
    half_t* kw = qw + 4194304;
    half_t* vw = kw + 4194304;             // transposed (bc,h,d,n)
    half_t* aw = vw + 4194304;

    k_convw<<<256, 256, 0, stream>>>(Wq, Wk, Wv, Wo, Wh);
    k_proj<<<dim3(512, 3), 256, 0, stream>>>(Q, K, V, Wh, qw, kw, vw);
    k_attn<<<1024, 256, 0, stream>>>(qw, kw, vw, mask, aw);
    k_out<<<512, 256, 0, stream>>>(aw, Wh + 49152, out);
}

// Round 3
// 182.270 us; speedup vs baseline: 1.0555x; 1.0324x over previous
//
#include <hip/hip_runtime.h>

typedef _Float16 half_t;
typedef _Float16 half8 __attribute__((ext_vector_type(8)));
typedef _Float16 half4 __attribute__((ext_vector_type(4)));
typedef float floatx4 __attribute__((ext_vector_type(4)));
typedef float floatx16 __attribute__((ext_vector_type(16)));

#define C1 0.72134752044448170368f   /* 2*log2(e)/SCALE, SCALE=4 */
#define C2 14.4269504088896340736f   /* 10*log2(e) */
#define C3 28.8539008177792681472f   /* 20*log2(e) */

__device__ __forceinline__ floatx4 zero4() {
    floatx4 z; z[0] = z[1] = z[2] = z[3] = 0.f; return z;
}
__device__ __forceinline__ floatx16 zero16() {
    floatx16 z;
#pragma unroll
    for (int i = 0; i < 16; ++i) z[i] = 0.f;
    return z;
}

// p = exp(10*tanh(s)) computed as exp2(b - C3 * rcp(exp2(S') + 1)),
// S' = 2*log2e*s (folded into Wq), b = C2 (unmasked) or -1e30 (masked -> p=0).
__device__ __forceinline__ float pfun(float sp, float b) {
    float u = __builtin_amdgcn_exp2f(sp);
    float r = __builtin_amdgcn_rcpf(u + 1.0f);
    return __builtin_amdgcn_exp2f(b - C3 * r);
}

// ---------------- k0: convert weights to fp16 (Wq pre-scaled by C1) --------
__global__ void k_convw(const float* __restrict__ Wq, const float* __restrict__ Wk,
                        const float* __restrict__ Wv, const float* __restrict__ Wo,
                        half_t* __restrict__ Wh) {
    int idx = blockIdx.x * 256 + threadIdx.x;      // 0..65535
    int which = idx >> 14;
    int off = idx & 16383;
    const float* src = (which == 0) ? Wq : (which == 1) ? Wk : (which == 2) ? Wv : Wo;
    float scale = (which == 0) ? C1 : 1.0f;
    Wh[idx] = (half_t)(src[off] * scale);
}

// ---------------- k1: QKV projections -------------------------------------
// Q,K: operand-swapped (A=W, B=X) -> D[f][token], half4 stores into
//      layout (bc, h, n, 16).
// V:   original order (A=X, B=W) -> D[token][f], half4 stores into
//      TRANSPOSED layout (bc, h, d, n) consumed directly by k_attn's PV MFMA.
__global__ __launch_bounds__(256) void k_proj(
        const float* __restrict__ Q, const float* __restrict__ K,
        const float* __restrict__ V, const half_t* __restrict__ WhBase,
        half_t* __restrict__ qw, half_t* __restrict__ kw, half_t* __restrict__ vw) {
    int which = blockIdx.y;
    const float* X = (which == 0) ? Q : (which == 1) ? K : V;
    const half_t* W = WhBase + which * 16384;

    int tid = threadIdx.x;
    int w = tid >> 6, lane = tid & 63;
    int l15 = lane & 15, quad = lane >> 4;
    int tokbase = blockIdx.x * 64 + w * 16;

    floatx4 acc[8];
#pragma unroll
    for (int nt = 0; nt < 8; ++nt) acc[nt] = zero4();

#pragma unroll
    for (int ks = 0; ks < 4; ++ks) {
        const float* ap = X + (tokbase + l15) * 128 + ks * 32 + quad * 8;
        float4 a0 = *(const float4*)ap;
        float4 a1 = *(const float4*)(ap + 4);
        half8 xf;
        xf[0] = (half_t)a0.x; xf[1] = (half_t)a0.y; xf[2] = (half_t)a0.z; xf[3] = (half_t)a0.w;
        xf[4] = (half_t)a1.x; xf[5] = (half_t)a1.y; xf[6] = (half_t)a1.z; xf[7] = (half_t)a1.w;
        if (which == 2) {
#pragma unroll
            for (int nt = 0; nt < 8; ++nt) {
                half8 wf = *(const half8*)(W + (nt * 16 + l15) * 128 + ks * 32 + quad * 8);
                acc[nt] = __builtin_amdgcn_mfma_f32_16x16x32_f16(xf, wf, acc[nt], 0, 0, 0);
            }
        } else {
#pragma unroll
            for (int nt = 0; nt < 8; ++nt) {
                half8 wf = *(const half8*)(W + (nt * 16 + l15) * 128 + ks * 32 + quad * 8);
                acc[nt] = __builtin_amdgcn_mfma_f32_16x16x32_f16(wf, xf, acc[nt], 0, 0, 0);
            }
        }
    }

    if (which == 2) {
        // D[token = quad*4+r][f = l15]; transposed store (bc, h, d, n)
        int R0 = tokbase + quad * 4;
        int bc = R0 >> 9, n0 = R0 & 511;
#pragma unroll
        for (int nt = 0; nt < 8; ++nt) {
            half4 hv;
            hv[0] = (half_t)acc[nt][0]; hv[1] = (half_t)acc[nt][1];
            hv[2] = (half_t)acc[nt][2]; hv[3] = (half_t)acc[nt][3];
            *(half4*)(vw + ((bc * 8 + nt) * 16 + l15) * 512 + n0) = hv;
        }
    } else {
        // D[f = quad*4+r][token = l15]; store (bc, h, n, 16)
        int R = tokbase + l15;
        int bc = R >> 9, n = R & 511;
        half_t* Y = (which == 0) ? qw : kw;
#pragma unroll
        for (int nt = 0; nt < 8; ++nt) {
            half4 hv;
            hv[0] = (half_t)acc[nt][0]; hv[1] = (half_t)acc[nt][1];
            hv[2] = (half_t)acc[nt][2]; hv[3] = (half_t)acc[nt][3];
            *(half4*)(Y + ((bc * 8 + nt) * 512 + n) * 16 + quad * 4) = hv;
        }
    }
}

// ---------------- k2: fused attention, one block per (bc, h, q-quarter) ---
// grid 2048 -> 8 blocks/CU, 32 waves/CU. Each wave: one 32-row q-tile.
__global__ __launch_bounds__(256, 8) void k_attn(
        const half_t* __restrict__ qg, const half_t* __restrict__ kg,
        const half_t* __restrict__ vTg, const int* __restrict__ mask,
        half_t* __restrict__ attn) {
    __shared__ float bias[512];
    __shared__ half_t Pl[4][32 * 36];        // per-wave P tile, row stride 36

    int bx = blockIdx.x;
    int bch = bx >> 2, qq = bx & 3;
    int bc = bch >> 3, h = bch & 7;
    int tid = threadIdx.x;
    int w = tid >> 6, lane = tid & 63;
    int l31 = lane & 31, hf = lane >> 5;
    int l15 = lane & 15, quad = lane >> 4;

    const half_t* qh = qg + bch * 8192;
    const half_t* kh = kg + bch * 8192;
    const half_t* vh = vTg + bch * 8192;     // (d, n): d*512 + n

    for (int i = tid; i < 512; i += 256)
        bias[i] = mask[bc * 512 + i] ? -1.0e30f : C2;
    __syncthreads();

    int qbase = qq * 128 + w * 32;
    // Q B-fragment (32x32x16): lane holds q[qrow = l31][d = hf*8 + j]
    half8 qf = *(const half8*)(qh + (qbase + l31) * 16 + hf * 8);

    floatx4 O[2];
    O[0] = zero4(); O[1] = zero4();
    float rs = 0.f;
    half_t* Pw = &Pl[w][0];
    const float4* b4 = (const float4*)bias;

#pragma unroll 1
    for (int c = 0; c < 16; ++c) {
        // K A-fragment: A[key = c*32 + l31][d = hf*8 + j]
        half8 kf = *(const half8*)(kh + (c * 32 + l31) * 16 + hf * 8);
        // V^T A-fragment for PV: A[d = l15][key = c*32 + quad*8 + j]
        half8 vf = *(const half8*)(vh + l15 * 512 + c * 32 + quad * 8);
        float4 bv[4];
#pragma unroll
        for (int g = 0; g < 4; ++g) bv[g] = b4[c * 8 + hf + 2 * g];

        // S^T tile: D[key][qrow], key = 8*(r>>2) + 4*hf + (r&3), qrow-local = l31
        floatx16 S = __builtin_amdgcn_mfma_f32_32x32x16_f16(kf, qf, zero16(), 0, 0, 0);
        float rsum = 0.f;
#pragma unroll
        for (int g = 0; g < 4; ++g) {
            float p0 = pfun(S[4 * g + 0], bv[g].x);
            float p1 = pfun(S[4 * g + 1], bv[g].y);
            float p2 = pfun(S[4 * g + 2], bv[g].z);
            float p3 = pfun(S[4 * g + 3], bv[g].w);
            rsum += (p0 + p1) + (p2 + p3);
            half4 ph;
            ph[0] = (half_t)p0; ph[1] = (half_t)p1;
            ph[2] = (half_t)p2; ph[3] = (half_t)p3;
            *(half4*)(Pw + l31 * 36 + hf * 4 + g * 8) = ph;
        }
        rs += rsum;
        // O^T += V^T * P^T for the two 16-col tiles of this 32-row P tile
#pragma unroll
        for (int nt2 = 0; nt2 < 2; ++nt2) {
            half8 pb = *(const half8*)(Pw + (nt2 * 16 + l15) * 36 + quad * 8);
            O[nt2] = __builtin_amdgcn_mfma_f32_16x16x32_f16(vf, pb, O[nt2], 0, 0, 0);
        }
    }

    float r2 = rs + __shfl_xor(rs, 32, 64);
    float inv = __builtin_amdgcn_rcpf(r2);
    // O^T C/D: row = d = quad*4 + r, col = qrow-local = nt*16 + l15
#pragma unroll
    for (int nt = 0; nt < 2; ++nt) {
        float iv = __shfl(inv, (nt << 4) | l15, 64);
        int qrow = qbase + nt * 16 + l15;
        half4 ov;
        ov[0] = (half_t)(O[nt][0] * iv);
        ov[1] = (half_t)(O[nt][1] * iv);
        ov[2] = (half_t)(O[nt][2] * iv);
        ov[3] = (half_t)(O[nt][3] * iv);
        *(half4*)(attn + (bc * 512 + qrow) * 128 + h * 16 + quad * 4) = ov;
    }
}

// ---------------- k3: output projection -> fp32 (operand-swapped) ----------
__global__ __launch_bounds__(256) void k_out(
        const half_t* __restrict__ A, const half_t* __restrict__ Wh,
        float* __restrict__ out) {
    int tid = threadIdx.x;
    int w = tid >> 6, lane = tid & 63;
    int l15 = lane & 15, quad = lane >> 4;
    int tokbase = blockIdx.x * 64 + w * 16;

    floatx4 acc[8];
#pragma unroll
    for (int nt = 0; nt < 8; ++nt) acc[nt] = zero4();
#pragma unroll
    for (int ks = 0; ks < 4; ++ks) {
        half8 xf = *(const half8*)(A + (tokbase + l15) * 128 + ks * 32 + quad * 8);
#pragma unroll
        for (int nt = 0; nt < 8; ++nt) {
            half8 wf = *(const half8*)(Wh + (nt * 16 + l15) * 128 + ks * 32 + quad * 8);
            acc[nt] = __builtin_amdgcn_mfma_f32_16x16x32_f16(wf, xf, acc[nt], 0, 0, 0);
        }
    }
    // D[f = nt*16 + quad*4 + r][token = l15] -> float4 stores
#pragma unroll
    for (int nt = 0; nt < 8; ++nt) {
        float4 o;
        o.x = acc[nt][0]; o.y = acc[nt][1]; o.z = acc[nt][2]; o.w = acc[nt][3];
        *(float4*)(out + (tokbase + l15) * 128 + nt * 16 + quad * 4) = o;
    }
}

extern "C" void kernel_launch(void* const* d_in, const int* in_sizes, int n_in,
                              void* d_out, int out_size, void* d_ws, size_t ws_size,
                              hipStream_t stream) {
    const float* Q    = (const float*)d_in[0];
    const float* K    = (const float*)d_in[1];
    const float* V    = (const float*)d_in[2];
    const int*   mask = (const int*)d_in[3];
    const float* Wq   = (const float*)d_in[4];
    const float* Wk   = (const float*)d_in[5];
    const float* Wv   = (const float*)d_in[6];
    const float* Wo   = (const float*)d_in[7];
    float* out = (float*)d_out;

    half_t* ws = (half_t*)d_ws;
    half_t* Wh = ws;                       // 65536 halves (4 x 128x128)
    half_t* qw = ws + 65536;               // each 4194304 halves
    half_t* kw = qw + 4194304;
    half_t* vw = kw + 4194304;             // transposed (bc,h,d,n)
    half_t* aw = vw + 4194304;

    k_convw<<<256, 256, 0, stream>>>(Wq, Wk, Wv, Wo, Wh);
    k_proj<<<dim3(512, 3), 256, 0, stream>>>(Q, K, V, Wh, qw, kw, vw);
    k_attn<<<2048, 256, 0, stream>>>(qw, kw, vw, mask, aw);
    k_out<<<512, 256, 0, stream>>>(aw, Wh + 49152, out);
}

// Round 5
// 180.066 us; speedup vs baseline: 1.0684x; 1.0122x over previous
//
#include <hip/hip_runtime.h>

typedef _Float16 half_t;
typedef _Float16 half8 __attribute__((ext_vector_type(8)));
typedef _Float16 half4 __attribute__((ext_vector_type(4)));
typedef float floatx4 __attribute__((ext_vector_type(4)));
typedef float floatx16 __attribute__((ext_vector_type(16)));

#define C1 0.72134752044448170368f   /* 2*log2(e)/SCALE, SCALE=4 */
#define C2 14.4269504088896340736f   /* 10*log2(e) */
#define C3 28.8539008177792681472f   /* 20*log2(e) */

__device__ __forceinline__ floatx4 zero4() {
    floatx4 z; z[0] = z[1] = z[2] = z[3] = 0.f; return z;
}
__device__ __forceinline__ floatx16 zero16() {
    floatx16 z;
#pragma unroll
    for (int i = 0; i < 16; ++i) z[i] = 0.f;
    return z;
}

// p = exp(10*tanh(s)) computed as exp2(b - C3 * rcp(exp2(S') + 1)),
// S' = 2*log2e*s (folded into Wq), b = C2 (unmasked) or -1e30 (masked -> p=0).
__device__ __forceinline__ float pfun(float sp, float b) {
    float u = __builtin_amdgcn_exp2f(sp);
    float r = __builtin_amdgcn_rcpf(u + 1.0f);
    return __builtin_amdgcn_exp2f(b - C3 * r);
}

// ---------------- k0: convert weights to fp16 (Wq pre-scaled by C1) --------
__global__ void k_convw(const float* __restrict__ Wq, const float* __restrict__ Wk,
                        const float* __restrict__ Wv, const float* __restrict__ Wo,
                        half_t* __restrict__ Wh) {
    int idx = blockIdx.x * 256 + threadIdx.x;      // 0..65535
    int which = idx >> 14;
    int off = idx & 16383;
    const float* src = (which == 0) ? Wq : (which == 1) ? Wk : (which == 2) ? Wv : Wo;
    float scale = (which == 0) ? C1 : 1.0f;
    Wh[idx] = (half_t)(src[off] * scale);
}

// ---------------- k1: QKV projections -------------------------------------
// Q,K: operand-swapped (A=W, B=X) -> D[f][token], half4 stores into
//      layout (bc, h, n, 16).
// V:   original order (A=X, B=W) -> D[token][f], half4 stores into
//      TRANSPOSED layout (bc, h, d, n) consumed directly by k_attn's PV MFMA.
__global__ __launch_bounds__(256) void k_proj(
        const float* __restrict__ Q, const float* __restrict__ K,
        const float* __restrict__ V, const half_t* __restrict__ WhBase,
        half_t* __restrict__ qw, half_t* __restrict__ kw, half_t* __restrict__ vw) {
    int which = blockIdx.y;
    const float* X = (which == 0) ? Q : (which == 1) ? K : V;
    const half_t* W = WhBase + which * 16384;

    int tid = threadIdx.x;
    int w = tid >> 6, lane = tid & 63;
    int l15 = lane & 15, quad = lane >> 4;
    int tokbase = blockIdx.x * 64 + w * 16;

    floatx4 acc[8];
#pragma unroll
    for (int nt = 0; nt < 8; ++nt) acc[nt] = zero4();

#pragma unroll
    for (int ks = 0; ks < 4; ++ks) {
        const float* ap = X + (tokbase + l15) * 128 + ks * 32 + quad * 8;
        float4 a0 = *(const float4*)ap;
        float4 a1 = *(const float4*)(ap + 4);
        half8 xf;
        xf[0] = (half_t)a0.x; xf[1] = (half_t)a0.y; xf[2] = (half_t)a0.z; xf[3] = (half_t)a0.w;
        xf[4] = (half_t)a1.x; xf[5] = (half_t)a1.y; xf[6] = (half_t)a1.z; xf[7] = (half_t)a1.w;
        if (which == 2) {
#pragma unroll
            for (int nt = 0; nt < 8; ++nt) {
                half8 wf = *(const half8*)(W + (nt * 16 + l15) * 128 + ks * 32 + quad * 8);
                acc[nt] = __builtin_amdgcn_mfma_f32_16x16x32_f16(xf, wf, acc[nt], 0, 0, 0);
            }
        } else {
#pragma unroll
            for (int nt = 0; nt < 8; ++nt) {
                half8 wf = *(const half8*)(W + (nt * 16 + l15) * 128 + ks * 32 + quad * 8);
                acc[nt] = __builtin_amdgcn_mfma_f32_16x16x32_f16(wf, xf, acc[nt], 0, 0, 0);
            }
        }
    }

    if (which == 2) {
        // D[token = quad*4+r][f = l15]; transposed store (bc, h, d, n)
        int R0 = tokbase + quad * 4;
        int bc = R0 >> 9, n0 = R0 & 511;
#pragma unroll
        for (int nt = 0; nt < 8; ++nt) {
            half4 hv;
            hv[0] = (half_t)acc[nt][0]; hv[1] = (half_t)acc[nt][1];
            hv[2] = (half_t)acc[nt][2]; hv[3] = (half_t)acc[nt][3];
            *(half4*)(vw + ((bc * 8 + nt) * 16 + l15) * 512 + n0) = hv;
        }
    } else {
        // D[f = quad*4+r][token = l15]; store (bc, h, n, 16)
        int R = tokbase + l15;
        int bc = R >> 9, n = R & 511;
        half_t* Y = (which == 0) ? qw : kw;
#pragma unroll
        for (int nt = 0; nt < 8; ++nt) {
            half4 hv;
            hv[0] = (half_t)acc[nt][0]; hv[1] = (half_t)acc[nt][1];
            hv[2] = (half_t)acc[nt][2]; hv[3] = (half_t)acc[nt][3];
            *(half4*)(Y + ((bc * 8 + nt) * 512 + n) * 16 + quad * 4) = hv;
        }
    }
}

// ---------------- k2: fused attention, ONE WAVE per block -----------------
// grid 8192 = (bc, h, q-16th). 32 blocks/CU = 32 waves/CU, fine-grained
// scheduling. Row sums computed on the MFMA pipe via a ones-vector MFMA
// (sum lands replicated in every lane -> lane-local rcp, no shuffles).
__global__ __launch_bounds__(64, 8) void k_attn(
        const half_t* __restrict__ qg, const half_t* __restrict__ kg,
        const half_t* __restrict__ vTg, const int* __restrict__ mask,
        half_t* __restrict__ attn) {
    __shared__ float bias[512];
    __shared__ half_t Pb[32 * 36];           // P tile, row stride 36

    int bx = blockIdx.x;
    int bch = bx >> 4, qt = bx & 15;
    int bc = bch >> 3, h = bch & 7;
    int lane = threadIdx.x;
    int l31 = lane & 31, hf = lane >> 5;
    int l15 = lane & 15, quad = lane >> 4;

    const half_t* qh = qg + bch * 8192;
    const half_t* kh = kg + bch * 8192;
    const half_t* vh = vTg + bch * 8192;     // (d, n): d*512 + n

#pragma unroll
    for (int i = 0; i < 8; ++i)
        bias[i * 64 + lane] = mask[bc * 512 + i * 64 + lane] ? -1.0e30f : C2;
    __syncthreads();

    int qbase = qt * 32;
    // Q B-fragment (32x32x16): lane holds q[qrow = l31][d = hf*8 + j]
    half8 qf = *(const half8*)(qh + (qbase + l31) * 16 + hf * 8);

    half8 ones;
#pragma unroll
    for (int j = 0; j < 8; ++j) ones[j] = (half_t)1.0f;

    floatx4 O[2], Os[2];
    O[0] = zero4(); O[1] = zero4();
    Os[0] = zero4(); Os[1] = zero4();
    const float4* b4 = (const float4*)bias;

#pragma unroll 1
    for (int c = 0; c < 16; ++c) {
        // K A-fragment: A[key = c*32 + l31][d = hf*8 + j]
        half8 kf = *(const half8*)(kh + (c * 32 + l31) * 16 + hf * 8);
        // V^T A-fragment for PV: A[d = l15][key = c*32 + quad*8 + j]
        half8 vf = *(const half8*)(vh + l15 * 512 + c * 32 + quad * 8);
        float4 bv[4];
#pragma unroll
        for (int g = 0; g < 4; ++g) bv[g] = b4[c * 8 + hf + 2 * g];

        // S^T tile: D[key][qrow], key = 8*(r>>2) + 4*hf + (r&3), qrow-local = l31
        floatx16 S = __builtin_amdgcn_mfma_f32_32x32x16_f16(kf, qf, zero16(), 0, 0, 0);
#pragma unroll
        for (int g = 0; g < 4; ++g) {
            float p0 = pfun(S[4 * g + 0], bv[g].x);
            float p1 = pfun(S[4 * g + 1], bv[g].y);
            float p2 = pfun(S[4 * g + 2], bv[g].z);
            float p3 = pfun(S[4 * g + 3], bv[g].w);
            auto t0 = __builtin_amdgcn_cvt_pkrtz(p0, p1);   // __fp16 x2
            auto t1 = __builtin_amdgcn_cvt_pkrtz(p2, p3);
            half4 ph;
            ph[0] = (half_t)t0[0]; ph[1] = (half_t)t0[1];
            ph[2] = (half_t)t1[0]; ph[3] = (half_t)t1[1];
            *(half4*)(Pb + l31 * 36 + hf * 4 + g * 8) = ph;
        }
        // O^T += V^T * P^T ; Os += ones * P^T (row sums on MFMA pipe)
#pragma unroll
        for (int nt2 = 0; nt2 < 2; ++nt2) {
            half8 pb = *(const half8*)(Pb + (nt2 * 16 + l15) * 36 + quad * 8);
            O[nt2]  = __builtin_amdgcn_mfma_f32_16x16x32_f16(vf,   pb, O[nt2],  0, 0, 0);
            Os[nt2] = __builtin_amdgcn_mfma_f32_16x16x32_f16(ones, pb, Os[nt2], 0, 0, 0);
        }
    }

    // Os C/D: every row holds the same value = rowsum(q = nt*16 + l15);
    // O C/D col is also q = l15 -> lane-local normalization, no shuffles.
#pragma unroll
    for (int nt = 0; nt < 2; ++nt) {
        float iv = __builtin_amdgcn_rcpf(Os[nt][0]);
        int qrow = qbase + nt * 16 + l15;
        half4 ov;
        ov[0] = (half_t)(O[nt][0] * iv);
        ov[1] = (half_t)(O[nt][1] * iv);
        ov[2] = (half_t)(O[nt][2] * iv);
        ov[3] = (half_t)(O[nt][3] * iv);
        *(half4*)(attn + (bc * 512 + qrow) * 128 + h * 16 + quad * 4) = ov;
    }
}

// ---------------- k3: output projection -> fp32 (operand-swapped) ----------
__global__ __launch_bounds__(256) void k_out(
        const half_t* __restrict__ A, const half_t* __restrict__ Wh,
        float* __restrict__ out) {
    int tid = threadIdx.x;
    int w = tid >> 6, lane = tid & 63;
    int l15 = lane & 15, quad = lane >> 4;
    int tokbase = blockIdx.x * 64 + w * 16;

    floatx4 acc[8];
#pragma unroll
    for (int nt = 0; nt < 8; ++nt) acc[nt] = zero4();
#pragma unroll
    for (int ks = 0; ks < 4; ++ks) {
        half8 xf = *(const half8*)(A + (tokbase + l15) * 128 + ks * 32 + quad * 8);
#pragma unroll
        for (int nt = 0; nt < 8; ++nt) {
            half8 wf = *(const half8*)(Wh + (nt * 16 + l15) * 128 + ks * 32 + quad * 8);
            acc[nt] = __builtin_amdgcn_mfma_f32_16x16x32_f16(wf, xf, acc[nt], 0, 0, 0);
        }
    }
    // D[f = nt*16 + quad*4 + r][token = l15] -> float4 stores
#pragma unroll
    for (int nt = 0; nt < 8; ++nt) {
        float4 o;
        o.x = acc[nt][0]; o.y = acc[nt][1]; o.z = acc[nt][2]; o.w = acc[nt][3];
        *(float4*)(out + (tokbase + l15) * 128 + nt * 16 + quad * 4) = o;
    }
}

extern "C" void kernel_launch(void* const* d_in, const int* in_sizes, int n_in,
                              void* d_out, int out_size, void* d_ws, size_t ws_size,
                              hipStream_t stream) {
    const float* Q    = (const float*)d_in[0];
    const float* K    = (const float*)d_in[1];
    const float* V    = (const float*)d_in[2];
    const int*   mask = (const int*)d_in[3];
    const float* Wq   = (const float*)d_in[4];
    const float* Wk   = (const float*)d_in[5];
    const float* Wv   = (const float*)d_in[6];
    const float* Wo   = (const float*)d_in[7];
    float* out = (float*)d_out;

    half_t* ws = (half_t*)d_ws;
    half_t* Wh = ws;                       // 65536 halves (4 x 128x128)
    half_t* qw = ws + 65536;               // each 4194304 halves
    half_t* kw = qw + 4194304;
    half_t* vw = kw + 4194304;             // transposed (bc,h,d,n)
    half_t* aw = vw + 4194304;

    k_convw<<<256, 256, 0, stream>>>(Wq, Wk, Wv, Wo, Wh);
    k_proj<<<dim3(512, 3), 256, 0, stream>>>(Q, K, V, Wh, qw, kw, vw);
    k_attn<<<8192, 64, 0, stream>>>(qw, kw, vw, mask, aw);
    k_out<<<512, 256, 0, stream>>>(aw, Wh + 49152, out);
}